// Round 10
// baseline (41.901 us; speedup 1.0000x reference)
//
#include <hip/hip_runtime.h>
#include <math.h>

constexpr int B_ = 64;
constexpr int Q_ = 300;
constexpr int T_ = 25;
constexpr int NCLS = 91;
constexpr int L_ = NCLS + 1;       // 92
constexpr float C_BB = 5.0f, C_GI = 2.0f;
constexpr float W_CE = 2.0f, W_BBOX = 2.5f, W_GIOU = 2.0f;
constexpr float EOS = 0.1f;
constexpr int K_ = 5;              // columns per lane (wave-level scans)
constexpr int TPB = 256;           // 4 waves

// exact monotone bijection f64 <-> u64 (unsigned order == float order)
__device__ __forceinline__ unsigned long long ord64(double v) {
    long long bb = __double_as_longlong(v);
    return (bb < 0) ? ~(unsigned long long)bb
                    : ((unsigned long long)bb | 0x8000000000000000ULL);
}
__device__ __forceinline__ double unord64(unsigned long long u) {
    long long bb = (u & 0x8000000000000000ULL) ? (long long)(u & 0x7FFFFFFFFFFFFFFFULL)
                                               : (long long)~u;
    return __longlong_as_double(bb);
}
// truncated packs (round value DOWN by <=~1e-12; r4/r7/r8-proven slop class)
__device__ __forceinline__ unsigned long long pack14(double v, unsigned aux) {
    return (ord64(v) & ~16383ULL) | (unsigned long long)aux;
}
__device__ __forceinline__ unsigned long long pack9(double v, unsigned col) {
    return (ord64(v) & ~511ULL) | (unsigned long long)col;
}

// lane permutes on u64 via 2x32
template <int CTRL>
__device__ __forceinline__ unsigned long long dppb(unsigned long long b) {
    int lo = __builtin_amdgcn_update_dpp(0, (int)(unsigned)b, CTRL, 0xF, 0xF, true);
    int hi = __builtin_amdgcn_update_dpp(0, (int)(unsigned)(b >> 32), CTRL, 0xF, 0xF, true);
    return ((unsigned long long)(unsigned)hi << 32) | (unsigned)lo;
}
__device__ __forceinline__ unsigned long long swz16(unsigned long long b) {
    int lo = __builtin_amdgcn_ds_swizzle((int)(unsigned)b, 0x401F);   // lane^16 in 32
    int hi = __builtin_amdgcn_ds_swizzle((int)(unsigned)(b >> 32), 0x401F);
    return ((unsigned long long)(unsigned)hi << 32) | (unsigned)lo;
}

// full-wave min of a single packed key
__device__ __forceinline__ unsigned long long wavemin(unsigned long long b) {
    { unsigned long long o = __shfl_xor(b, 32); if (o < b) b = o; }
    { unsigned long long o = swz16(b);      if (o < b) b = o; }
    { unsigned long long o = dppb<0x140>(b); if (o < b) b = o; }  // row_mirror
    { unsigned long long o = dppb<0x141>(b); if (o < b) b = o; }  // half_mirror
    { unsigned long long o = dppb<0x4E>(b);  if (o < b) b = o; }  // lane^2
    { unsigned long long o = dppb<0xB1>(b);  if (o < b) b = o; }  // lane^1
    return b;
}
// top-2 merge of sorted pairs from disjoint lane-sets
__device__ __forceinline__ void red2(unsigned long long& k1, unsigned long long& k2,
                                     unsigned long long o1, unsigned long long o2) {
    unsigned long long n1 = o1 < k1 ? o1 : k1;
    unsigned long long ls = o1 < k1 ? k1 : o1;
    unsigned long long n2 = k2 < o2 ? k2 : o2;
    n2 = ls < n2 ? ls : n2;
    k1 = n1; k2 = n2;
}
// full-wave (min, second-min): merge sets disjoint at every stage
__device__ __forceinline__ void wavemin2(unsigned long long& k1, unsigned long long& k2) {
    red2(k1, k2, __shfl_xor(k1, 32), __shfl_xor(k2, 32));
    red2(k1, k2, swz16(k1), swz16(k2));
    red2(k1, k2, dppb<0x140>(k1), dppb<0x140>(k2));
    red2(k1, k2, dppb<0x141>(k1), dppb<0x141>(k2));
    red2(k1, k2, dppb<0x4E>(k1),  dppb<0x4E>(k2));
    red2(k1, k2, dppb<0xB1>(k1),  dppb<0xB1>(k2));
}

__device__ __forceinline__ float giou_f(const float px[4], float parea,
                                        const float tx[4], float tarea) {
    float ltx = fmaxf(px[0], tx[0]), lty = fmaxf(px[1], tx[1]);
    float rbx = fminf(px[2], tx[2]), rby = fminf(px[3], tx[3]);
    float iw = fmaxf(rbx - ltx, 0.f), ih = fmaxf(rby - lty, 0.f);
    float inter = iw * ih;
    float uni = parea + tarea - inter;
    float iou = inter / uni;
    float lix = fminf(px[0], tx[0]), liy = fminf(px[1], tx[1]);
    float rix = fmaxf(px[2], tx[2]), riy = fmaxf(px[3], tx[3]);
    float aw = fmaxf(rix - lix, 0.f), ah = fmaxf(riy - liy, 0.f);
    float ai = aw * ah;
    return iou - (ai - uni) / ai;
}

__global__ __launch_bounds__(TPB) void fused_kernel(
        const float* __restrict__ logits,
        const float* __restrict__ pboxes,
        const int*   __restrict__ tlabels,
        const float* __restrict__ tboxes,
        double* acc,          // [3] f64 partial sums + u32 counter (zeroed by memset)
        float* out) {
    const int b = blockIdx.x;
    const int tid = threadIdx.x;

    __shared__ float  costL[T_][Q_];    // 30000 B
    __shared__ float  lseL[Q_];
    __shared__ double vL[Q_];           // column duals (f64)
    __shared__ int    pL[Q_ + 1];       // col(1-based) -> row(1-based), 0 free
    __shared__ int    wayL[Q_ + 1];
    __shared__ double uL[T_ + 1];       // row duals
    __shared__ int    argcolL[T_];
    __shared__ float  m1L[T_];          // exact row min
    __shared__ double m2L[T_];          // second min (pack-trunc class)
    __shared__ int    bidRowL[4];
    __shared__ int    bidJL[4];
    __shared__ double bidM1L[4], bidM2L[4];
    __shared__ unsigned freemaskL;
    __shared__ int    mqL[T_];
    __shared__ int    lblL[T_];
    __shared__ int    lblq[Q_];
    __shared__ float  tbL[T_][4];
    __shared__ float  txL[T_][4];
    __shared__ float  taL[T_];
    __shared__ double wsum[4][3];

    // ---- preload targets + init ----
    if (tid < T_) {
        lblL[tid] = tlabels[b * T_ + tid];
        mqL[tid] = 0;                    // defensive
        float c0 = tboxes[(size_t)(b * T_ + tid) * 4 + 0];
        float c1 = tboxes[(size_t)(b * T_ + tid) * 4 + 1];
        float c2 = tboxes[(size_t)(b * T_ + tid) * 4 + 2];
        float c3 = tboxes[(size_t)(b * T_ + tid) * 4 + 3];
        tbL[tid][0] = c0; tbL[tid][1] = c1; tbL[tid][2] = c2; tbL[tid][3] = c3;
        float x0 = c0 - 0.5f * c2, y0 = c1 - 0.5f * c3;
        float x1 = c0 + 0.5f * c2, y1 = c1 + 0.5f * c3;
        txL[tid][0] = x0; txL[tid][1] = y0; txL[tid][2] = x1; txL[tid][3] = y1;
        taL[tid] = (x1 - x0) * (y1 - y0);
    }
    for (int j = tid; j <= Q_; j += TPB) { pL[j] = 0; wayL[j] = 0; }
    for (int q = tid; q < Q_; q += TPB) { lblq[q] = NCLS; vL[q] = 0.0; }
    __syncthreads();

    const float* lgb = logits + (size_t)b * Q_ * L_;
    const float* pbb = pboxes + (size_t)b * Q_ * 4;

    // ---- cost build (all 4 waves) ----
    for (int q = tid; q < Q_; q += TPB) {
        const float4* lr4 = (const float4*)(lgb + (size_t)q * L_);  // 92 = 23*4
        float m0 = -INFINITY, m1 = -INFINITY, m2 = -INFINITY, m3 = -INFINITY;
        for (int c = 0; c < 23; ++c) {
            float4 v = lr4[c];
            m0 = fmaxf(m0, v.x); m1 = fmaxf(m1, v.y);
            m2 = fmaxf(m2, v.z); m3 = fmaxf(m3, v.w);
        }
        float mx = fmaxf(fmaxf(m0, m1), fmaxf(m2, m3));
        float s0 = 0.f, s1 = 0.f, s2 = 0.f, s3 = 0.f;
        for (int c = 0; c < 23; ++c) {
            float4 v = lr4[c];
            s0 += expf(v.x - mx); s1 += expf(v.y - mx);
            s2 += expf(v.z - mx); s3 += expf(v.w - mx);
        }
        float lz = mx + logf((s0 + s1) + (s2 + s3));
        lseL[q] = lz;

        float p0 = pbb[(size_t)q * 4 + 0], p1 = pbb[(size_t)q * 4 + 1];
        float p2 = pbb[(size_t)q * 4 + 2], p3 = pbb[(size_t)q * 4 + 3];
        float px[4] = { p0 - 0.5f * p2, p1 - 0.5f * p3, p0 + 0.5f * p2, p1 + 0.5f * p3 };
        float parea = (px[2] - px[0]) * (px[3] - px[1]);

#pragma unroll
        for (int t = 0; t < T_; ++t) {
            float cls = lz - lgb[(size_t)q * L_ + lblL[t]];
            float l1 = fabsf(p0 - tbL[t][0]) + fabsf(p1 - tbL[t][1]) +
                       fabsf(p2 - tbL[t][2]) + fabsf(p3 - tbL[t][3]);
            float tx[4] = { txL[t][0], txL[t][1], txL[t][2], txL[t][3] };
            float g = giou_f(px, parea, tx, taL[t]);
            costL[t][q] = C_BB * l1 + cls - C_GI * g;
        }
    }
    __syncthreads();

    // ---- row (min, argmin, 2nd min) on RAW costs (v=0), 4 waves ----
    {
        int w = tid >> 6, lane = tid & 63;
        for (int t = w; t < T_; t += 4) {
            unsigned long long k1 = ~0ULL, k2 = ~0ULL;
#pragma unroll
            for (int k = 0; k < K_; ++k) {
                int col = lane + 64 * k;
                if (col < Q_) {
                    unsigned long long kk = pack9((double)costL[t][col], (unsigned)col);
                    if (kk < k1) { k2 = k1; k1 = kk; }
                    else if (kk < k2) { k2 = kk; }
                }
            }
            wavemin2(k1, k2);
            if (lane == 0) {
                int jc = (int)(k1 & 511ULL);
                argcolL[t] = jc;
                m1L[t] = costL[t][jc];               // exact row min
                m2L[t] = unord64(k2 & ~511ULL);      // trunc-class 2nd min
            }
        }
    }
    __syncthreads();

    // ---- round 1 (mass Jacobi auction): winners award in parallel (wave 0).
    // Invariants henceforth: v<=0 and only decreases, only matched columns
    // have v<0, matched edges tight (trunc class), duals feasible.
    if (tid < 64) {
        bool isrow = (tid >= 1 && tid <= T_);
        int r0 = tid - 1;
        int myc = isrow ? argcolL[r0] : -1;
        bool winner = isrow;
        if (isrow) {
            for (int j = 0; j < r0; ++j)
                if (argcolL[j] == myc) winner = false;
        }
        if (isrow) {
            uL[tid] = winner ? m2L[r0] : (double)m1L[r0];
            if (winner) {
                pL[myc + 1] = tid;                 // row (1-based)
                double d = m2L[r0] - (double)m1L[r0];
                if (d < 0.0) d = 0.0;
                vL[myc] = -d;                      // from 0
            }
        }
        unsigned long long mbal = __ballot(isrow && winner);
        if (tid == 0) freemaskL = (~(unsigned)(mbal >> 1)) & ((1u << T_) - 1);
    }

    // ---- Jacobi auction rounds: up to 4 free rows per round (1 per wave) ----
    for (int round = 0; round < 40; ++round) {
        __syncthreads();
        unsigned fm = freemaskL;
        if (!fm) break;
        int w = tid >> 6, lane = tid & 63;
        unsigned m = fm;
        for (int i = 0; i < w; ++i) m &= m - 1;
        int myrow = m ? (int)__builtin_ctz(m) : -1;   // 0-based free row
        unsigned long long k1 = ~0ULL, k2 = ~0ULL;
        if (myrow >= 0) {
            const float* crow = &costL[myrow][0];
#pragma unroll
            for (int k = 0; k < K_; ++k) {
                int col = lane + 64 * k;
                if (col < Q_) {
                    double cur = (double)crow[col] - vL[col];
                    unsigned long long kk = pack9(cur, (unsigned)col);
                    if (kk < k1) { k2 = k1; k1 = kk; }
                    else if (kk < k2) { k2 = kk; }
                }
            }
            wavemin2(k1, k2);
        }
        if (lane == 0) {
            bidRowL[w] = myrow;
            if (myrow >= 0) {
                bidJL[w]  = (int)(k1 & 511ULL);
                bidM1L[w] = unord64(k1 & ~511ULL);
                bidM2L[w] = unord64(k2 & ~511ULL);
            }
        }
        __syncthreads();
        if (tid == 0) {           // resolve <=4 bids; distinct cols only
            int c0 = -1, c1 = -1, c2 = -1;
            unsigned f2 = fm;
            for (int ww = 0; ww < 4; ++ww) {
                int r = bidRowL[ww];
                if (r < 0) continue;
                int j = bidJL[ww];
                if (j == c0 || j == c1 || j == c2) continue;   // loser stays free
                if (c0 < 0) c0 = j; else if (c1 < 0) c1 = j; else c2 = j;
                double d = bidM2L[ww] - bidM1L[ww];
                if (d < 0.0) d = 0.0;
                int prev = pL[j + 1];
                pL[j + 1] = r + 1;
                uL[r + 1] = bidM2L[ww];
                vL[j] -= d;
                f2 &= ~(1u << r);
                if (prev) f2 |= 1u << (prev - 1);
            }
            freemaskL = f2;
        }
    }
    __syncthreads();

    // ---- wave 0: exact shortest-augmenting-path phases for leftovers ----
    if (tid < 64) {
        unsigned freemask = freemaskL;
        double v0[K_], minv[K_], stampv[K_];
        int pReg[K_];
        bool usedk[K_], validk[K_];
#pragma unroll
        for (int k = 0; k < K_; ++k) {
            int col = tid + 64 * k;
            validk[k] = col < Q_;
            v0[k] = validk[k] ? vL[col] : 0.0;
            stampv[k] = 0.0; usedk[k] = false; minv[k] = INFINITY;
            pReg[k] = validk[k] ? pL[col + 1] : 0;
        }

        for (int i = 1; i <= T_; ++i) {
            if (!((freemask >> (i - 1)) & 1u)) continue;
            if (tid == 0) pL[0] = i;
#pragma unroll
            for (int k = 0; k < K_; ++k) { minv[k] = INFINITY; usedk[k] = false; }
            double S = 0.0;
            int j0 = 0, i0 = i;
            double u0i0 = uL[i];

            for (int step = 0; step < 512; ++step) {
                double a = u0i0 - S;
                const float* crow = &costL[i0 - 1][0];
                unsigned long long bk = ~0ULL;
#pragma unroll
                for (int k = 0; k < K_; ++k) {
                    if (validk[k] && !usedk[k]) {
                        int col = tid + 64 * k;
                        double cur = (double)crow[col] - a - v0[k];
                        if (cur < minv[k]) { minv[k] = cur; wayL[col + 1] = j0; }
                        unsigned long long kk = pack14(
                            minv[k], ((unsigned)(col + 1) << 5) | (unsigned)pReg[k]);
                        if (kk < bk) bk = kk;
                    }
                }
                bk = wavemin(bk);
                int j1  = (int)((bk >> 5) & 511ULL);   // 1-based col
                int i0n = (int)(bk & 31ULL);
                double Snew = unord64(bk & ~16383ULL);
                S = Snew;
                j0 = j1;
                if (i0n == 0) break;
                int owner = (j1 - 1) & 63, k1i = (j1 - 1) >> 6;
                if (tid == owner) {
#pragma unroll
                    for (int k = 0; k < K_; ++k)
                        if (k == k1i) { usedk[k] = true; stampv[k] = Snew; }
                }
                i0 = i0n;
                u0i0 = uL[i0];
            }

            // phase-end dual updates (pre-augment p; distinct rows per lane)
#pragma unroll
            for (int k = 0; k < K_; ++k) {
                if (validk[k] && usedk[k]) {
                    double d = S - stampv[k];
                    v0[k] -= d;
                    uL[pReg[k]] += d;
                }
            }
            if (tid == 0) {
                uL[i] += S;
                int jj = j0;
                while (jj) { int jn = wayL[jj]; pL[jj] = pL[jn]; jj = jn; }
            }
#pragma unroll
            for (int k = 0; k < K_; ++k)
                if (validk[k]) pReg[k] = pL[tid + 1 + 64 * k];
        }

        // matching -> per-target query, per-query label
#pragma unroll
        for (int k = 0; k < K_; ++k)
            if (validk[k] && pReg[k] > 0) mqL[pReg[k] - 1] = tid + 64 * k;
        if (tid < T_) lblq[mqL[tid]] = lblL[tid];
    }
    __syncthreads();

    // ---- losses (all 4 waves) ----
    double ce = 0.0, sb = 0.0, sg = 0.0;
    for (int q = tid; q < Q_; q += TPB) {
        int label = lblq[q];
        float nll = lseL[q] - lgb[(size_t)q * L_ + label];
        float w = (label == NCLS) ? EOS : 1.0f;
        ce += (double)(w * nll);
    }
    if (tid < T_) {
        int q = mqL[tid];
        float p0 = pbb[(size_t)q * 4 + 0], p1 = pbb[(size_t)q * 4 + 1];
        float p2 = pbb[(size_t)q * 4 + 2], p3 = pbb[(size_t)q * 4 + 3];
        sb = (double)(fabsf(p0 - tbL[tid][0]) + fabsf(p1 - tbL[tid][1]) +
                      fabsf(p2 - tbL[tid][2]) + fabsf(p3 - tbL[tid][3]));
        float px[4] = { p0 - 0.5f * p2, p1 - 0.5f * p3, p0 + 0.5f * p2, p1 + 0.5f * p3 };
        float parea = (px[2] - px[0]) * (px[3] - px[1]);
        float tx[4] = { txL[tid][0], txL[tid][1], txL[tid][2], txL[tid][3] };
        float g = giou_f(px, parea, tx, taL[tid]);
        sg = (double)(1.0f - g);
    }
#pragma unroll
    for (int off = 1; off < 64; off <<= 1) {
        ce += __shfl_xor(ce, off);
        sb += __shfl_xor(sb, off);
        sg += __shfl_xor(sg, off);
    }
    if ((tid & 63) == 0) {
        int w = tid >> 6;
        wsum[w][0] = ce; wsum[w][1] = sb; wsum[w][2] = sg;
    }
    __syncthreads();

    // ---- cross-block f64 accumulation + last-block finalize ----
    if (tid == 0) {
        double a0 = 0, a1 = 0, a2 = 0;
        for (int w = 0; w < 4; ++w) { a0 += wsum[w][0]; a1 += wsum[w][1]; a2 += wsum[w][2]; }
        atomicAdd(&acc[0], a0);
        atomicAdd(&acc[1], a1);
        atomicAdd(&acc[2], a2);
        __threadfence();
        unsigned* cnt = (unsigned*)(acc + 3);
        unsigned old = atomicAdd(cnt, 1u);
        if (old == (unsigned)(B_ - 1)) {
            __threadfence();
            double A = atomicAdd(&acc[0], 0.0);   // coherent read-back
            double C = atomicAdd(&acc[1], 0.0);
            double G = atomicAdd(&acc[2], 0.0);
            // w.sum() = 64*(25*1.0 + 275*0.1) = 3360 ; num_t = 64*25 = 1600
            float lce = W_CE * (float)(A / 3360.0);
            float lbb = W_BBOX * (float)(C / 1600.0);
            float lgi = W_GIOU * (float)(G / 1600.0);
            out[0] = lce;
            out[1] = lbb;
            out[2] = lgi;
            out[3] = lce + lbb + lgi;
        }
    }
}

extern "C" void kernel_launch(void* const* d_in, const int* in_sizes, int n_in,
                              void* d_out, int out_size, void* d_ws, size_t ws_size,
                              hipStream_t stream) {
    (void)in_sizes; (void)n_in; (void)out_size; (void)ws_size;
    const float* logits  = (const float*)d_in[0];   // [B,Q,92] f32
    const float* pboxes  = (const float*)d_in[1];   // [B,Q,4]  f32
    const int*   tlabels = (const int*)d_in[2];     // [B,T]    i32
    const float* tboxes  = (const float*)d_in[3];   // [B,T,4]  f32
    float* out = (float*)d_out;
    double* acc = (double*)d_ws;                    // 3 f64 + u32 counter

    hipMemsetAsync(d_ws, 0, 64, stream);
    fused_kernel<<<B_, TPB, 0, stream>>>(logits, pboxes, tlabels, tboxes, acc, out);
}

// Round 11
// 36.470 us; speedup vs baseline: 1.1489x; 1.1489x over previous
//
#include <hip/hip_runtime.h>
#include <math.h>

constexpr int B_ = 64;
constexpr int Q_ = 300;
constexpr int T_ = 25;
constexpr int NCLS = 91;
constexpr int L_ = NCLS + 1;       // 92
constexpr float C_BB = 5.0f, C_GI = 2.0f;
constexpr float W_CE = 2.0f, W_BBOX = 2.5f, W_GIOU = 2.0f;
constexpr float EOS = 0.1f;
constexpr int K_ = 5;              // columns per lane in JV (wave 0)
constexpr int TPB = 256;           // 4 waves

// exact monotone bijection f64 <-> u64 (unsigned order == float order)
__device__ __forceinline__ unsigned long long ord64(double v) {
    long long bb = __double_as_longlong(v);
    return (bb < 0) ? ~(unsigned long long)bb
                    : ((unsigned long long)bb | 0x8000000000000000ULL);
}
__device__ __forceinline__ double unord64(unsigned long long u) {
    long long bb = (u & 0x8000000000000000ULL) ? (long long)(u & 0x7FFFFFFFFFFFFFFFULL)
                                               : (long long)~u;
    return __longlong_as_double(bb);
}
// exact monotone map f32 -> u32
__device__ __forceinline__ unsigned int ord32(float f) {
    unsigned int b = __float_as_uint(f);
    return (b & 0x80000000u) ? ~b : (b | 0x80000000u);
}
// truncated packs (truncation rounds value DOWN; ~1e-13 class, r3/r4/r7/r8-proven)
__device__ __forceinline__ unsigned long long pack14(double v, unsigned aux) {
    return (ord64(v) & ~16383ULL) | (unsigned long long)aux;
}
__device__ __forceinline__ unsigned long long pack9(double v, unsigned col) {
    return (ord64(v) & ~511ULL) | (unsigned long long)col;
}

// u64 lane permute via 2x32 DPP (VALU-speed, no LDS crossbar)
template <int CTRL>
__device__ __forceinline__ unsigned long long dppb(unsigned long long b) {
    int lo = __builtin_amdgcn_update_dpp(0, (int)(unsigned)b, CTRL, 0xF, 0xF, true);
    int hi = __builtin_amdgcn_update_dpp(0, (int)(unsigned)(b >> 32), CTRL, 0xF, 0xF, true);
    return ((unsigned long long)(unsigned)hi << 32) | (unsigned)lo;
}
__device__ __forceinline__ unsigned long long bcast63(unsigned long long b) {
    unsigned lo = (unsigned)__builtin_amdgcn_readlane((int)(unsigned)b, 63);
    unsigned hi = (unsigned)__builtin_amdgcn_readlane((int)(unsigned)(b >> 32), 63);
    return ((unsigned long long)hi << 32) | lo;
}
__device__ __forceinline__ double readlane_f64(double v, int lane) {
    long long b = __double_as_longlong(v);
    int lo = __builtin_amdgcn_readlane((int)(unsigned)(unsigned long long)b, lane);
    int hi = __builtin_amdgcn_readlane((int)(((unsigned long long)b) >> 32), lane);
    return __longlong_as_double((long long)(((unsigned long long)(unsigned)hi << 32)
                                           | (unsigned)lo));
}

// all-DPP wave64 min; stages: xor1,xor2,xor4,xor8 (within 16-row), then
// ROW_BCAST15/31 fold rows into lane 63. bound_ctrl zero-fill corrupts only
// lanes that never feed lane 63. Returns wave-uniform min via readlane(63).
__device__ __forceinline__ unsigned long long wavemin(unsigned long long b) {
    { unsigned long long o = dppb<0xB1>(b);  if (o < b) b = o; }  // xor1
    { unsigned long long o = dppb<0x4E>(b);  if (o < b) b = o; }  // xor2
    { unsigned long long o = dppb<0x141>(b); if (o < b) b = o; }  // xor4 half_mirror
    { unsigned long long o = dppb<0x140>(b); if (o < b) b = o; }  // xor8 row_mirror
    { unsigned long long o = dppb<0x142>(b); if (o < b) b = o; }  // row_bcast15
    { unsigned long long o = dppb<0x143>(b); if (o < b) b = o; }  // row_bcast31
    return bcast63(b);
}
// top-2 merge of sorted pairs from disjoint lane-sets
__device__ __forceinline__ void red2(unsigned long long& k1, unsigned long long& k2,
                                     unsigned long long o1, unsigned long long o2) {
    unsigned long long n1 = o1 < k1 ? o1 : k1;
    unsigned long long ls = o1 < k1 ? k1 : o1;
    unsigned long long n2 = k2 < o2 ? k2 : o2;
    n2 = ls < n2 ? ls : n2;
    k1 = n1; k2 = n2;
}
// all-DPP wave64 (min, 2nd min); lane-63 path merges disjoint sets only
// (row3{r2,r3} ∪ lane31{r0,r1}) so both values are exact. Uniform result.
__device__ __forceinline__ void wavemin2(unsigned long long& k1, unsigned long long& k2) {
    red2(k1, k2, dppb<0xB1>(k1),  dppb<0xB1>(k2));
    red2(k1, k2, dppb<0x4E>(k1),  dppb<0x4E>(k2));
    red2(k1, k2, dppb<0x141>(k1), dppb<0x141>(k2));
    red2(k1, k2, dppb<0x140>(k1), dppb<0x140>(k2));
    red2(k1, k2, dppb<0x142>(k1), dppb<0x142>(k2));
    red2(k1, k2, dppb<0x143>(k1), dppb<0x143>(k2));
    k1 = bcast63(k1);
    k2 = bcast63(k2);
}

__device__ __forceinline__ float giou_f(const float px[4], float parea,
                                        const float tx[4], float tarea) {
    float ltx = fmaxf(px[0], tx[0]), lty = fmaxf(px[1], tx[1]);
    float rbx = fminf(px[2], tx[2]), rby = fminf(px[3], tx[3]);
    float iw = fmaxf(rbx - ltx, 0.f), ih = fmaxf(rby - lty, 0.f);
    float inter = iw * ih;
    float uni = parea + tarea - inter;
    float iou = inter / uni;
    float lix = fminf(px[0], tx[0]), liy = fminf(px[1], tx[1]);
    float rix = fmaxf(px[2], tx[2]), riy = fmaxf(px[3], tx[3]);
    float aw = fmaxf(rix - lix, 0.f), ah = fmaxf(riy - liy, 0.f);
    float ai = aw * ah;
    return iou - (ai - uni) / ai;
}

__global__ __launch_bounds__(TPB) void fused_kernel(
        const float* __restrict__ logits,
        const float* __restrict__ pboxes,
        const int*   __restrict__ tlabels,
        const float* __restrict__ tboxes,
        double* __restrict__ partial) {
    const int b = blockIdx.x;
    const int tid = threadIdx.x;

    __shared__ float  costL[T_][Q_];    // 30000 B
    __shared__ float  lseL[Q_];
    __shared__ int    pL[Q_ + 1];       // col(1-based) -> row(1-based), 0 free
    __shared__ int    wayL[Q_ + 1];
    __shared__ double uL[T_ + 1];       // row duals (staging)
    __shared__ double uStage[32];
    __shared__ int    argcolL[T_];
    __shared__ int    mqL[T_];
    __shared__ int    lblL[T_];
    __shared__ int    lblq[Q_];
    __shared__ float  tbL[T_][4];
    __shared__ float  txL[T_][4];
    __shared__ float  taL[T_];
    __shared__ double wsum[4][3];

    // ---- preload targets + init ----
    if (tid < T_) {
        lblL[tid] = tlabels[b * T_ + tid];
        mqL[tid] = 0;                    // defensive
        float c0 = tboxes[(size_t)(b * T_ + tid) * 4 + 0];
        float c1 = tboxes[(size_t)(b * T_ + tid) * 4 + 1];
        float c2 = tboxes[(size_t)(b * T_ + tid) * 4 + 2];
        float c3 = tboxes[(size_t)(b * T_ + tid) * 4 + 3];
        tbL[tid][0] = c0; tbL[tid][1] = c1; tbL[tid][2] = c2; tbL[tid][3] = c3;
        float x0 = c0 - 0.5f * c2, y0 = c1 - 0.5f * c3;
        float x1 = c0 + 0.5f * c2, y1 = c1 + 0.5f * c3;
        txL[tid][0] = x0; txL[tid][1] = y0; txL[tid][2] = x1; txL[tid][3] = y1;
        taL[tid] = (x1 - x0) * (y1 - y0);
    }
    for (int j = tid; j <= Q_; j += TPB) { pL[j] = 0; wayL[j] = 0; }
    for (int q = tid; q < Q_; q += TPB) lblq[q] = NCLS;
    __syncthreads();

    const float* lgb = logits + (size_t)b * Q_ * L_;
    const float* pbb = pboxes + (size_t)b * Q_ * 4;

    // ---- cost build (all 4 waves) ----
    for (int q = tid; q < Q_; q += TPB) {
        const float4* lr4 = (const float4*)(lgb + (size_t)q * L_);  // 92 = 23*4
        float m0 = -INFINITY, m1 = -INFINITY, m2 = -INFINITY, m3 = -INFINITY;
        for (int c = 0; c < 23; ++c) {
            float4 v = lr4[c];
            m0 = fmaxf(m0, v.x); m1 = fmaxf(m1, v.y);
            m2 = fmaxf(m2, v.z); m3 = fmaxf(m3, v.w);
        }
        float mx = fmaxf(fmaxf(m0, m1), fmaxf(m2, m3));
        float s0 = 0.f, s1 = 0.f, s2 = 0.f, s3 = 0.f;
        for (int c = 0; c < 23; ++c) {
            float4 v = lr4[c];
            s0 += expf(v.x - mx); s1 += expf(v.y - mx);
            s2 += expf(v.z - mx); s3 += expf(v.w - mx);
        }
        float lz = mx + logf((s0 + s1) + (s2 + s3));
        lseL[q] = lz;

        float p0 = pbb[(size_t)q * 4 + 0], p1 = pbb[(size_t)q * 4 + 1];
        float p2 = pbb[(size_t)q * 4 + 2], p3 = pbb[(size_t)q * 4 + 3];
        float px[4] = { p0 - 0.5f * p2, p1 - 0.5f * p3, p0 + 0.5f * p2, p1 + 0.5f * p3 };
        float parea = (px[2] - px[0]) * (px[3] - px[1]);

#pragma unroll
        for (int t = 0; t < T_; ++t) {
            float cls = lz - lgb[(size_t)q * L_ + lblL[t]];
            float l1 = fabsf(p0 - tbL[t][0]) + fabsf(p1 - tbL[t][1]) +
                       fabsf(p2 - tbL[t][2]) + fabsf(p3 - tbL[t][3]);
            float tx[4] = { txL[t][0], txL[t][1], txL[t][2], txL[t][3] };
            float g = giou_f(px, parea, tx, taL[t]);
            costL[t][q] = C_BB * l1 + cls - C_GI * g;
        }
    }
    __syncthreads();

    // ---- row minima on RAW costs (v=0), exact ord32|col keys, 4 waves ----
    {
        int w = tid >> 6, lane = tid & 63;
        for (int t = w; t < T_; t += 4) {
            unsigned long long best = ~0ULL;
#pragma unroll
            for (int k = 0; k < K_; ++k) {
                int col = lane + 64 * k;
                if (col < Q_) {
                    unsigned long long kk =
                        ((unsigned long long)ord32(costL[t][col]) << 32) | (unsigned)col;
                    if (kk < best) best = kk;
                }
            }
            best = wavemin(best);
            if (lane == 0) {
                int jc = (int)(best & 0xFFFFFFFFULL);
                argcolL[t] = jc;
                uL[t + 1] = (double)costL[t][jc];   // exact row min (v=0)
            }
        }
    }
    __syncthreads();

    // =====================================================================
    // Wave 0: greedy (v=0) + LAPJV augmenting-row-reduction + exact phases.
    // Invariants: v<=0 and only decreases, unmatched cols keep v=0, matched
    // edges tight (up to ~1e-13 pack slack), duals feasible ==> completion
    // equals the reference rectangular-LAP optimum.  (r8-measured structure,
    // reduces swapped to all-DPP + readlane.)
    // =====================================================================
    if (tid < 64) {
        // greedy: row wins its raw-argmin column iff smallest proposer
        int win = tid;
        if (tid < T_) {
            int myc = argcolL[tid];
            for (int j = 0; j < T_; ++j) {
                int oc = argcolL[j];
                if (oc == myc && j < win) win = j;
            }
            if (win == tid) pL[myc + 1] = tid + 1;
        }
        unsigned long long mb = __ballot(tid < T_ && win == tid);
        unsigned int freemask = (~(unsigned int)mb) & ((1u << T_) - 1);

        // per-lane column state; per-lane row-dual mirror (lane l = u[l])
        double v0[K_], minv[K_], stampv[K_];
        int pReg[K_];
        bool usedk[K_], validk[K_];
        double ureg = (tid >= 1 && tid <= T_) ? uL[tid] : 0.0;
#pragma unroll
        for (int k = 0; k < K_; ++k) {
            int col = tid + 64 * k;
            validk[k] = col < Q_;
            v0[k] = 0.0;
            stampv[k] = 0.0; usedk[k] = false; minv[k] = INFINITY;
            pReg[k] = validk[k] ? pL[col + 1] : 0;
        }

        // ---- augmenting row reduction (register-only; capped) ----
        for (int iter = 0; iter < 48 && freemask; ++iter) {
            int t = __builtin_ctz(freemask);       // 0-based free row
            freemask &= freemask - 1;
            const float* crow = &costL[t][0];
            unsigned long long k1 = ~0ULL, k2 = ~0ULL;
#pragma unroll
            for (int k = 0; k < K_; ++k) {
                if (validk[k]) {
                    int col = tid + 64 * k;
                    unsigned long long kk = pack9((double)crow[col] - v0[k], (unsigned)col);
                    if (kk < k1) { k2 = k1; k1 = kk; }
                    else if (kk < k2) { k2 = kk; }
                }
            }
            wavemin2(k1, k2);
            int j1 = (int)(k1 & 511ULL);           // 0-based col
            double am1 = unord64(k1 & ~511ULL);
            double am2 = unord64(k2 & ~511ULL);
            int owner = j1 & 63, k1i = j1 >> 6;
            int psel = pReg[0];
#pragma unroll
            for (int k = 1; k < K_; ++k)
                if (k1i == k) psel = pReg[k];
            int prev = __builtin_amdgcn_readlane(psel, owner);  // displaced row (1-based)
            if (tid == owner) {
#pragma unroll
                for (int k = 0; k < K_; ++k)
                    if (k == k1i) { v0[k] -= (am2 - am1); pReg[k] = t + 1; }
            }
            if (tid == t + 1) ureg = am2;          // u[t] = second min
            if (prev) freemask |= 1u << (prev - 1);
        }

        // write back column->row map for the phase solver
#pragma unroll
        for (int k = 0; k < K_; ++k)
            if (validk[k]) pL[tid + 1 + 64 * k] = pReg[k];

        // ---- exact shortest-augmenting-path phases for leftover rows ----
        for (int i = 1; i <= T_; ++i) {
            if (!((freemask >> (i - 1)) & 1u)) continue;
            if (tid == 0) pL[0] = i;
#pragma unroll
            for (int k = 0; k < K_; ++k) { minv[k] = INFINITY; usedk[k] = false; }
            double S = 0.0;
            int j0 = 0, i0 = i;
            double u0i0 = readlane_f64(ureg, i);

            for (int step = 0; step < 512; ++step) {
                double a = u0i0 - S;
                const float* crow = &costL[i0 - 1][0];
                unsigned long long bk = ~0ULL;
#pragma unroll
                for (int k = 0; k < K_; ++k) {
                    if (validk[k] && !usedk[k]) {
                        int col = tid + 64 * k;
                        double cur = (double)crow[col] - a - v0[k];
                        if (cur < minv[k]) { minv[k] = cur; wayL[col + 1] = j0; }
                        unsigned long long kk = pack14(
                            minv[k], ((unsigned)(col + 1) << 5) | (unsigned)pReg[k]);
                        if (kk < bk) bk = kk;
                    }
                }
                bk = wavemin(bk);
                int j1  = (int)((bk >> 5) & 511ULL);   // 1-based col
                int i0n = (int)(bk & 31ULL);
                double Snew = unord64(bk & ~16383ULL);
                S = Snew;
                j0 = j1;
                if (i0n == 0) break;
                int owner = (j1 - 1) & 63, k1i = (j1 - 1) >> 6;
                if (tid == owner) {
#pragma unroll
                    for (int k = 0; k < K_; ++k)
                        if (k == k1i) { usedk[k] = true; stampv[k] = Snew; }
                }
                i0 = i0n;
                u0i0 = readlane_f64(ureg, i0);
            }

            // phase-end dual updates (pre-augment p; distinct rows per lane)
            if (tid <= T_) uStage[tid] = 0.0;
#pragma unroll
            for (int k = 0; k < K_; ++k) {
                if (validk[k] && usedk[k]) {
                    double d = S - stampv[k];
                    v0[k] -= d;
                    uStage[pReg[k]] = d;
                }
            }
            if (tid >= 1 && tid <= T_) ureg += uStage[tid];
            if (tid == i) ureg += S;
            if (tid == 0) {
                int jj = j0;
                while (jj) { int jn = wayL[jj]; pL[jj] = pL[jn]; jj = jn; }
            }
#pragma unroll
            for (int k = 0; k < K_; ++k)
                if (validk[k]) pReg[k] = pL[tid + 1 + 64 * k];
        }

        // matching -> per-target query, per-query label
#pragma unroll
        for (int k = 0; k < K_; ++k)
            if (validk[k] && pReg[k] > 0) mqL[pReg[k] - 1] = tid + 64 * k;
        if (tid < T_) lblq[mqL[tid]] = lblL[tid];
    }
    __syncthreads();

    // ---- losses (all 4 waves) ----
    double ce = 0.0, sb = 0.0, sg = 0.0;
    for (int q = tid; q < Q_; q += TPB) {
        int label = lblq[q];
        float nll = lseL[q] - lgb[(size_t)q * L_ + label];
        float w = (label == NCLS) ? EOS : 1.0f;
        ce += (double)(w * nll);
    }
    if (tid < T_) {
        int q = mqL[tid];
        float p0 = pbb[(size_t)q * 4 + 0], p1 = pbb[(size_t)q * 4 + 1];
        float p2 = pbb[(size_t)q * 4 + 2], p3 = pbb[(size_t)q * 4 + 3];
        sb = (double)(fabsf(p0 - tbL[tid][0]) + fabsf(p1 - tbL[tid][1]) +
                      fabsf(p2 - tbL[tid][2]) + fabsf(p3 - tbL[tid][3]));
        float px[4] = { p0 - 0.5f * p2, p1 - 0.5f * p3, p0 + 0.5f * p2, p1 + 0.5f * p3 };
        float parea = (px[2] - px[0]) * (px[3] - px[1]);
        float tx[4] = { txL[tid][0], txL[tid][1], txL[tid][2], txL[tid][3] };
        float g = giou_f(px, parea, tx, taL[tid]);
        sg = (double)(1.0f - g);
    }
#pragma unroll
    for (int off = 1; off < 64; off <<= 1) {
        ce += __shfl_xor(ce, off);
        sb += __shfl_xor(sb, off);
        sg += __shfl_xor(sg, off);
    }
    if ((tid & 63) == 0) {
        int w = tid >> 6;
        wsum[w][0] = ce; wsum[w][1] = sb; wsum[w][2] = sg;
    }
    __syncthreads();
    if (tid == 0) {
        double a0 = 0, a1 = 0, a2 = 0;
        for (int w = 0; w < 4; ++w) { a0 += wsum[w][0]; a1 += wsum[w][1]; a2 += wsum[w][2]; }
        partial[(size_t)b * 3 + 0] = a0;
        partial[(size_t)b * 3 + 1] = a1;
        partial[(size_t)b * 3 + 2] = a2;
    }
}

__global__ __launch_bounds__(64) void finalize_kernel(const double* __restrict__ partial,
                                                      float* __restrict__ out) {
    int tid = threadIdx.x;
    double a = partial[(size_t)tid * 3 + 0];
    double c = partial[(size_t)tid * 3 + 1];
    double g = partial[(size_t)tid * 3 + 2];
#pragma unroll
    for (int off = 1; off < 64; off <<= 1) {
        a += __shfl_xor(a, off);
        c += __shfl_xor(c, off);
        g += __shfl_xor(g, off);
    }
    if (tid == 0) {
        // w.sum() = 64*(25*1.0 + 275*0.1) = 3360 ; num_t = 64*25 = 1600
        float lce = W_CE * (float)(a / 3360.0);
        float lbb = W_BBOX * (float)(c / 1600.0);
        float lgi = W_GIOU * (float)(g / 1600.0);
        out[0] = lce;
        out[1] = lbb;
        out[2] = lgi;
        out[3] = lce + lbb + lgi;
    }
}

extern "C" void kernel_launch(void* const* d_in, const int* in_sizes, int n_in,
                              void* d_out, int out_size, void* d_ws, size_t ws_size,
                              hipStream_t stream) {
    (void)in_sizes; (void)n_in; (void)out_size; (void)ws_size;
    const float* logits  = (const float*)d_in[0];   // [B,Q,92] f32
    const float* pboxes  = (const float*)d_in[1];   // [B,Q,4]  f32
    const int*   tlabels = (const int*)d_in[2];     // [B,T]    i32
    const float* tboxes  = (const float*)d_in[3];   // [B,T,4]  f32
    float* out = (float*)d_out;
    double* partial = (double*)d_ws;                // [64][3] f64

    fused_kernel<<<B_, TPB, 0, stream>>>(logits, pboxes, tlabels, tboxes, partial);
    finalize_kernel<<<1, 64, 0, stream>>>(partial, out);
}